// Round 14
// baseline (300.977 us; speedup 1.0000x reference)
//
#include <hip/hip_runtime.h>

typedef __attribute__((ext_vector_type(8))) short short8;
typedef __attribute__((ext_vector_type(4))) float f32x4;
typedef __attribute__((ext_vector_type(16))) float f32x16;
typedef __attribute__((ext_vector_type(4))) unsigned short us4;
typedef __attribute__((ext_vector_type(2))) unsigned int u32x2;

#define NTOK 343
#define BMP 352      // bias/mask padded row pitch (elements)
#define LOG2E 1.4426950408889634f
#define FPLANE 11264 // shorts per (b,h) fragment plane: 11 tiles x 1024
#define WPITCH 200   // LDS W row pitch (shorts)

// ---- workspace layout (bytes) ----
#define OFF_QG   0u            // q: [bh][tok][32]            33,718,272
#define OFF_KG   33718272u     // k frag planes: 1536*11264*2 34,603,008
#define OFF_VT   68321280u     // v frag planes               34,603,008
#define OFF_AO   102924288u    // attn out                    33,718,272
#define OFF_WB   136642560u    // bf16 weights
// f32 bias/mask tables live in d_out scratch (dead before proj_out writes):
//   bias_f: outc + 0          (6*343*352*4  = 2,897,664)
//   mask_f: outc + 2,897,664  (64*343*352*4 = 30,908,416; end 33,806,080 < 67,436,544)

__device__ __forceinline__ unsigned short f2bf(float f) {
  union { float f; unsigned u; } v; v.f = f;
  unsigned r = v.u + 0x7FFFu + ((v.u >> 16) & 1u);
  return (unsigned short)(r >> 16);
}

__device__ __forceinline__ short8 ld8(const unsigned short* p) {
  return *reinterpret_cast<const short8*>(p);
}

__device__ __forceinline__ float fexp2(float x) {
  float r; asm("v_exp_f32 %0, %1" : "=v"(r) : "v"(x)); return r;
}

__device__ __forceinline__ unsigned cvtpk(float a, float b) {
  unsigned r; asm("v_cvt_pk_bf16_f32 %0, %1, %2" : "=v"(r) : "v"(a), "v"(b)); return r;
}

// D' = {D.lo32lanes, S.lo32lanes}; S' = {D.hi32lanes, S.hi32lanes}
__device__ __forceinline__ void plswap(unsigned &a, unsigned &b) {
  asm("v_permlane32_swap_b32 %0, %1" : "+v"(a), "+v"(b));
}

__device__ __forceinline__ f32x16 mfma32(short8 a, short8 b, f32x16 c) {
  return __builtin_amdgcn_mfma_f32_32x32x16_bf16(a, b, c, 0, 0, 0);
}

__device__ __forceinline__ f32x4 mfma16(short8 a, short8 b, f32x4 c) {
  return __builtin_amdgcn_mfma_f32_16x16x32_bf16(a, b, c, 0, 0, 0);
}

union frag_u { unsigned u[4]; short8 s8; };

// pack 8 consecutive f32 -> bf16x8 fragment
__device__ __forceinline__ short8 cvt8f(const float* p) {
  f32x4 a = *reinterpret_cast<const f32x4*>(p);
  f32x4 b = *reinterpret_cast<const f32x4*>(p + 4);
  frag_u f;
  f.u[0] = cvtpk(a[0], a[1]); f.u[1] = cvtpk(a[2], a[3]);
  f.u[2] = cvtpk(b[0], b[1]); f.u[3] = cvtpk(b[2], b[3]);
  return f.s8;
}

// ---------------- kernel B: precompute (weights bf16, bias/mask f32, pads) ----------------
// task ranges:
//  [0, 36864)             weights -> bf16 (vec4)
//  [36864, 1968640)       mask -> mask_f * LOG2E (21952 rows x 88 f32x4, pad-zeroed)
//  [1968640, 2086289)     bias gather * LOG2E -> f32 (117649, x6 heads)
//  [2086289, 2088347)     bias pad zero (2058 rows x 9)
//  [2088347, 2284955)     v_frag tile-10 zero (1536 bh x 128 chunks)
__global__ __launch_bounds__(256) void precompute(
    const float* __restrict__ mask, const float* __restrict__ table,
    const int* __restrict__ rel_idx,
    const float* __restrict__ qw, const float* __restrict__ kvw, const float* __restrict__ pw,
    unsigned short* __restrict__ wq_bf, unsigned short* __restrict__ wkv_bf,
    unsigned short* __restrict__ wp_bf,
    float* __restrict__ bias_f, float* __restrict__ mask_f,
    unsigned short* __restrict__ v_frag)
{
  const int idx = blockIdx.x * 256 + threadIdx.x;
  if (idx < 36864) {
    const int wi = idx;
    const float* src; unsigned short* dst; int i;
    if (wi < 9216)       { src = qw;  dst = wq_bf;  i = wi; }
    else if (wi < 27648) { src = kvw; dst = wkv_bf; i = wi - 9216; }
    else                 { src = pw;  dst = wp_bf;  i = wi - 27648; }
    f32x4 v = *reinterpret_cast<const f32x4*>(src + i * 4);
    us4 o; o[0] = f2bf(v[0]); o[1] = f2bf(v[1]); o[2] = f2bf(v[2]); o[3] = f2bf(v[3]);
    *reinterpret_cast<us4*>(dst + i * 4) = o;
  } else if (idx < 1968640) {
    const int mi = idx - 36864;
    const int row = mi / 88, q = mi - row * 88;
    const int j0 = q * 4;
    float* dst = mask_f + row * BMP + j0;
    if (q < 85) {
      const float* src = mask + row * NTOK + j0;
      f32x4 o; o[0] = LOG2E * src[0]; o[1] = LOG2E * src[1];
      o[2] = LOG2E * src[2]; o[3] = LOG2E * src[3];
      *reinterpret_cast<f32x4*>(dst) = o;
    } else {
      f32x4 o;
      #pragma unroll
      for (int i = 0; i < 4; ++i) {
        const int col = j0 + i;
        o[i] = (col < NTOK) ? (LOG2E * mask[row * NTOK + col]) : 0.f;
      }
      *reinterpret_cast<f32x4*>(dst) = o;
    }
  } else if (idx < 2086289) {
    const int i = idx - 1968640;
    const int ri = rel_idx[i] * 6;
    const int rrow = i / NTOK, j = i - rrow * NTOK;
    float* dst = bias_f + rrow * BMP + j;
    #pragma unroll
    for (int h = 0; h < 6; ++h) dst[h * (NTOK * BMP)] = LOG2E * table[ri + h];
  } else if (idx < 2088347) {
    const int p = idx - 2086289;
    float* dst = bias_f + p * BMP + NTOK;
    #pragma unroll
    for (int c = 0; c < 9; ++c) dst[c] = 0.f;
  } else if (idx < 2284955) {
    const int i = idx - 2088347;
    const int bh = i >> 7, c = i & 127;
    short8 z = (short8){0,0,0,0,0,0,0,0};
    *reinterpret_cast<short8*>(v_frag + bh * FPLANE + 10240 + c * 8) = z;
  }
}

// ---------------- kernel A: fused Q/K/V projection (f32 X, LDS-W, per-window tiles) ----------------
__global__ __launch_bounds__(256) void proj(
    const float* __restrict__ x1f, const float* __restrict__ x2f,
    const unsigned short* __restrict__ wq_bf, const unsigned short* __restrict__ wkv_bf,
    const float* __restrict__ qb, const float* __restrict__ kvb,
    unsigned short* __restrict__ q_g, unsigned short* __restrict__ k_g,
    unsigned short* __restrict__ v_frag)
{
  __shared__ __align__(16) unsigned short wLds[192 * WPITCH];

  const int tid = threadIdx.x;
  const int wv = tid >> 6, lane = tid & 63, lg = lane >> 4, lr = lane & 15;
  const int path = blockIdx.y;
  const int b = blockIdx.x & 255, seg = blockIdx.x >> 8;
  const int n0 = seg * 128 + wv * 32;

  const float* X = (path == 0) ? x1f : x2f;
  const unsigned short* Wsrc = (path == 0) ? wq_bf : (path == 1 ? wkv_bf : wkv_bf + 36864);

  #pragma unroll
  for (int i = 0; i < 18; ++i) {
    const int c = i * 256 + tid;
    const int row = c / 24, c8 = c - row * 24;
    *reinterpret_cast<short8*>(&wLds[row * WPITCH + c8 * 8]) = ld8(Wsrc + row * 192 + c8 * 8);
  }
  __syncthreads();

  const int rowbase = b * NTOK;
  const int nA = n0 + lr, nB = n0 + 16 + lr;
  const float* xr0 = X + (rowbase + (nA < NTOK ? nA : NTOK - 1)) * 192 + lg * 8;
  const float* xr1 = X + (rowbase + (nB < NTOK ? nB : NTOK - 1)) * 192 + lg * 8;

  // load f32 fragments, convert to bf16 in-register
  short8 ax[2][6];
  #pragma unroll
  for (int kk = 0; kk < 6; ++kk) {
    ax[0][kk] = cvt8f(xr0 + kk * 32);
    ax[1][kk] = cvt8f(xr1 + kk * 32);
  }

  f32x4 acc[2][12];
  #pragma unroll
  for (int i = 0; i < 2; ++i)
    #pragma unroll
    for (int j = 0; j < 12; ++j) acc[i][j] = (f32x4){0.f, 0.f, 0.f, 0.f};

  if (path < 2) {
    #pragma unroll
    for (int kk = 0; kk < 6; ++kk) {
      const int k0 = kk * 32 + lg * 8;
      #pragma unroll
      for (int ct = 0; ct < 12; ++ct) {
        const short8 wf = *reinterpret_cast<const short8*>(&wLds[(ct * 16 + lr) * WPITCH + k0]);
        acc[0][ct] = mfma16(wf, ax[0][kk], acc[0][ct]);
        acc[1][ct] = mfma16(wf, ax[1][kk], acc[1][ct]);
      }
    }
    if (path == 0) {
      const float qs = 0.17677669529663687f * LOG2E;
      #pragma unroll
      for (int tt = 0; tt < 2; ++tt) {
        const int n = n0 + tt * 16 + lr;
        if (n < NTOK) {
          unsigned short* ob = q_g + (b * 6 * NTOK + n) * 32;
          #pragma unroll
          for (int ct = 0; ct < 12; ++ct) {
            const f32x4 bb = *reinterpret_cast<const f32x4*>(qb + ct * 16 + lg * 4);
            u32x2 pk;
            pk[0] = cvtpk((acc[tt][ct][0] + bb[0]) * qs, (acc[tt][ct][1] + bb[1]) * qs);
            pk[1] = cvtpk((acc[tt][ct][2] + bb[2]) * qs, (acc[tt][ct][3] + bb[3]) * qs);
            *reinterpret_cast<u32x2*>(ob + (ct >> 1) * (NTOK * 32) + (ct & 1) * 16 + lg * 4) = pk;
          }
        }
      }
    } else {
      #pragma unroll
      for (int tt = 0; tt < 2; ++tt) {
        const int n = n0 + tt * 16 + lr;
        if (n < 352) {
          unsigned short* ob = k_g + b * 6 * FPLANE + (n >> 5) * 1024
                               + ((lg >> 1) * 32 + (n & 31)) * 8 + (lg & 1) * 4;
          #pragma unroll
          for (int ct = 0; ct < 12; ++ct) {
            const f32x4 bb = *reinterpret_cast<const f32x4*>(kvb + ct * 16 + lg * 4);
            u32x2 pk;
            pk[0] = cvtpk(acc[tt][ct][0] + bb[0], acc[tt][ct][1] + bb[1]);
            pk[1] = cvtpk(acc[tt][ct][2] + bb[2], acc[tt][ct][3] + bb[3]);
            *reinterpret_cast<u32x2*>(ob + (ct >> 1) * FPLANE + (ct & 1) * 512) = pk;
          }
        }
      }
    }
  } else {
    #pragma unroll
    for (int kk = 0; kk < 6; ++kk) {
      const int k0 = kk * 32 + lg * 8;
      #pragma unroll
      for (int ct = 0; ct < 12; ++ct) {
        const short8 wf = *reinterpret_cast<const short8*>(&wLds[(ct * 16 + lr) * WPITCH + k0]);
        acc[0][ct] = mfma16(ax[0][kk], wf, acc[0][ct]);
        acc[1][ct] = mfma16(ax[1][kk], wf, acc[1][ct]);
      }
    }
    float bs[12];
    #pragma unroll
    for (int ct = 0; ct < 12; ++ct) bs[ct] = kvb[192 + ct * 16 + lr];
    #pragma unroll
    for (int tt = 0; tt < 2; ++tt) {
      const int nb = n0 + tt * 16 + lg * 4;
      if (nb < 352) {
        unsigned short* vb = v_frag + b * 6 * FPLANE + (nb >> 5) * 1024
                             + ((nb >> 4) & 1) * 512 + ((nb >> 3) & 1) * 256 + (nb & 7);
        #pragma unroll
        for (int ct = 0; ct < 12; ++ct) {
          const int d = (ct & 1) * 16 + lr;
          u32x2 pk;
          pk[0] = cvtpk(acc[tt][ct][0] + bs[ct], acc[tt][ct][1] + bs[ct]);
          pk[1] = cvtpk(acc[tt][ct][2] + bs[ct], acc[tt][ct][3] + bs[ct]);
          *reinterpret_cast<u32x2*>(vb + (ct >> 1) * FPLANE + d * 8) = pk;
        }
      }
    }
  }
}

// ---------------- kernel C: attention v14 (512 thr / 2 blocks/CU, f32 bias+mask) ----------------
__global__ __launch_bounds__(512, 4) void attn(
    const unsigned short* __restrict__ q_g, const unsigned short* __restrict__ k_g,
    const unsigned short* __restrict__ v_frag, const float* __restrict__ bias_f,
    const float* __restrict__ mask_f, unsigned short* __restrict__ attn_out)
{
  __shared__ __align__(16) unsigned short kvlds[2][FPLANE];

  const int tid = threadIdx.x;
  const int wv = tid >> 6, lane = tid & 63;
  const int l31 = lane & 31, hi = lane >> 5;
  // XCD-bijective decode: 4 b's sharing a (w,h) bias/mask panel land on one XCD
  const int s0 = blockIdx.x;
  const int xcd = s0 & 7, ii = s0 >> 3;
  const int g = xcd * 48 + (ii >> 2), mem = ii & 3;
  const int h = g >> 6, w = g & 63;
  const int b = mem * 64 + w;
  const int bid = b * 6 + h;

  const unsigned short* qp = q_g + bid * (NTOK * 32);
  const unsigned short* kpf = k_g + bid * FPLANE;
  const unsigned short* vpf = v_frag + bid * FPLANE;
  const float* bias_h = bias_f + h * (NTOK * BMP);
  const float* mask_w = mask_f + w * (NTOK * BMP);

  // stage K and V planes (linear copy, coalesced, conflict-free)
  #pragma unroll
  for (int j = 0; j < 3; ++j) {
    const int c = j * 512 + tid;
    if (c < 1408) {
      *reinterpret_cast<short8*>(&kvlds[0][c * 8]) = ld8(kpf + c * 8);
      *reinterpret_cast<short8*>(&kvlds[1][c * 8]) = ld8(vpf + c * 8);
    }
  }
  __syncthreads();

  for (int qt = wv; qt < 11; qt += 8) {
    const int qq = qt * 32 + l31;
    const int qrc = qq < NTOK ? qq : NTOK - 1;
    const short8 qf0 = ld8(qp + qrc * 32 + hi * 8);
    const short8 qf1 = ld8(qp + qrc * 32 + 16 + hi * 8);
    const float* bmb = bias_h + qrc * BMP + hi * 4;
    const float* bmm = mask_w + qrc * BMP + hi * 4;

    f32x16 O;
    #pragma unroll
    for (int r = 0; r < 16; ++r) O[r] = 0.f;
    f32x4 sacc = (f32x4){0.f, 0.f, 0.f, 0.f};

    // prefetch bias/mask for kt=0
    f32x4 nb[4], nm[4];
    #pragma unroll
    for (int gg = 0; gg < 4; ++gg) {
      nb[gg] = *reinterpret_cast<const f32x4*>(bmb + gg * 8);
      nm[gg] = *reinterpret_cast<const f32x4*>(bmm + gg * 8);
    }

    #pragma unroll
    for (int kt = 0; kt < 11; ++kt) {
      f32x4 cb[4], cm[4];
      #pragma unroll
      for (int gg = 0; gg < 4; ++gg) { cb[gg] = nb[gg]; cm[gg] = nm[gg]; }
      if (kt < 10) {
        const int kn = (kt + 1) * 32;
        #pragma unroll
        for (int gg = 0; gg < 4; ++gg) {
          nb[gg] = *reinterpret_cast<const f32x4*>(bmb + kn + gg * 8);
          nm[gg] = *reinterpret_cast<const f32x4*>(bmm + kn + gg * 8);
        }
      }

      // S^T tile from LDS fragments
      const short8 kf0 = ld8(&kvlds[0][kt * 1024 + lane * 8]);
      const short8 kf1 = ld8(&kvlds[0][kt * 1024 + 512 + lane * 8]);
      f32x16 sv;
      #pragma unroll
      for (int r = 0; r < 16; ++r) sv[r] = 0.f;
      __builtin_amdgcn_s_setprio(1);
      sv = mfma32(kf0, qf0, sv);
      sv = mfma32(kf1, qf1, sv);
      __builtin_amdgcn_s_setprio(0);

      // p = exp2(S + bias + mask) — no max subtraction (inputs bounded, f32-safe)
      float p[16];
      #pragma unroll
      for (int gg = 0; gg < 4; ++gg) {
        #pragma unroll
        for (int j = 0; j < 4; ++j) {
          float v = sv[gg * 4 + j] + (cb[gg][j] + cm[gg][j]);
          if (kt == 10 && (gg * 8 + hi * 4 + j) >= 23) v = -3.0e38f;
          p[gg * 4 + j] = fexp2(v);
        }
      }
      #pragma unroll
      for (int j = 0; j < 4; ++j)
        sacc[j] += (p[j] + p[4 + j]) + (p[8 + j] + p[12 + j]);

      unsigned c01 = cvtpk(p[0], p[1]),   c23 = cvtpk(p[2], p[3]);
      unsigned c45 = cvtpk(p[4], p[5]),   c67 = cvtpk(p[6], p[7]);
      unsigned d01 = cvtpk(p[8], p[9]),   d23 = cvtpk(p[10], p[11]);
      unsigned d45 = cvtpk(p[12], p[13]), d67 = cvtpk(p[14], p[15]);
      plswap(c01, c45); plswap(c23, c67);
      plswap(d01, d45); plswap(d23, d67);
      frag_u P0, P1;
      P0.u[0] = c01; P0.u[1] = c23; P0.u[2] = c45; P0.u[3] = c67;
      P1.u[0] = d01; P1.u[1] = d23; P1.u[2] = d45; P1.u[3] = d67;

      const short8 vf0 = ld8(&kvlds[1][kt * 1024 + lane * 8]);
      const short8 vf1 = ld8(&kvlds[1][kt * 1024 + 512 + lane * 8]);
      __builtin_amdgcn_s_setprio(1);
      O = mfma32(vf0, P0.s8, O);
      O = mfma32(vf1, P1.s8, O);
      __builtin_amdgcn_s_setprio(0);
    }

    float sum = (sacc[0] + sacc[1]) + (sacc[2] + sacc[3]);
    sum += __shfl_xor(sum, 32);
    const float inv = 1.0f / sum;
    if (qq < NTOK) {
      unsigned short* op = attn_out + (b * NTOK + qq) * 192 + h * 32;
      #pragma unroll
      for (int gg = 0; gg < 4; ++gg) {
        us4 ov;
        #pragma unroll
        for (int j = 0; j < 4; ++j) ov[j] = f2bf(O[gg * 4 + j] * inv);
        *reinterpret_cast<us4*>(op + gg * 8 + hi * 4) = ov;
      }
    }
  }
}

// ---------------- kernel D: output projection (LDS-W, swapped, f32x4 stores) ----------------
__global__ __launch_bounds__(256) void proj_out(
    const unsigned short* __restrict__ a_in, const unsigned short* __restrict__ wp_bf,
    const float* __restrict__ pb, float* __restrict__ out)
{
  __shared__ __align__(16) unsigned short wLds[192 * WPITCH];

  const int tid = threadIdx.x;
  const int wv = tid >> 6, lane = tid & 63, lg = lane >> 4, lr = lane & 15;
  const int t0 = blockIdx.x * 128 + wv * 32;

  #pragma unroll
  for (int i = 0; i < 18; ++i) {
    const int c = i * 256 + tid;
    const int row = c / 24, c8 = c - row * 24;
    *reinterpret_cast<short8*>(&wLds[row * WPITCH + c8 * 8]) = ld8(wp_bf + row * 192 + c8 * 8);
  }
  __syncthreads();

  const unsigned short* xr0 = a_in + (t0 + lr) * 192 + lg * 8;
  const unsigned short* xr1 = xr0 + 16 * 192;

  short8 ax[2][6];
  #pragma unroll
  for (int kk = 0; kk < 6; ++kk) {
    ax[0][kk] = ld8(xr0 + kk * 32);
    ax[1][kk] = ld8(xr1 + kk * 32);
  }

  f32x4 acc[2][12];
  #pragma unroll
  for (int i = 0; i < 2; ++i)
    #pragma unroll
    for (int j = 0; j < 12; ++j) acc[i][j] = (f32x4){0.f, 0.f, 0.f, 0.f};

  #pragma unroll
  for (int kk = 0; kk < 6; ++kk) {
    const int k0 = kk * 32 + lg * 8;
    #pragma unroll
    for (int ct = 0; ct < 12; ++ct) {
      const short8 wf = *reinterpret_cast<const short8*>(&wLds[(ct * 16 + lr) * WPITCH + k0]);
      acc[0][ct] = mfma16(wf, ax[0][kk], acc[0][ct]);
      acc[1][ct] = mfma16(wf, ax[1][kk], acc[1][ct]);
    }
  }

  #pragma unroll
  for (int tt = 0; tt < 2; ++tt) {
    const int t = t0 + tt * 16 + lr;
    float* op = out + t * 192 + lg * 4;
    #pragma unroll
    for (int ct = 0; ct < 12; ++ct) {
      const f32x4 bb = *reinterpret_cast<const f32x4*>(pb + ct * 16 + lg * 4);
      f32x4 ov;
      #pragma unroll
      for (int r = 0; r < 4; ++r) ov[r] = acc[tt][ct][r] + bb[r];
      *reinterpret_cast<f32x4*>(op + ct * 16) = ov;
    }
  }
}

extern "C" void kernel_launch(void* const* d_in, const int* in_sizes, int n_in,
                              void* d_out, int out_size, void* d_ws, size_t ws_size,
                              hipStream_t stream) {
  const float* x1    = (const float*)d_in[0];
  const float* x2    = (const float*)d_in[1];
  const float* mask  = (const float*)d_in[2];
  const float* table = (const float*)d_in[3];
  const float* qw    = (const float*)d_in[4];
  const float* qb    = (const float*)d_in[5];
  const float* kvw   = (const float*)d_in[6];
  const float* kvb   = (const float*)d_in[7];
  const float* pw    = (const float*)d_in[8];
  const float* pb    = (const float*)d_in[9];
  const int* rel_idx = (const int*)d_in[10];

  char* ws = (char*)d_ws;
  char* outc = (char*)d_out;
  unsigned short* q_g     = (unsigned short*)(ws + OFF_QG);
  unsigned short* k_g     = (unsigned short*)(ws + OFF_KG);
  unsigned short* v_frag  = (unsigned short*)(ws + OFF_VT);
  unsigned short* a_o     = (unsigned short*)(ws + OFF_AO);
  unsigned short* wq_bf   = (unsigned short*)(ws + OFF_WB);
  unsigned short* wkv_bf  = wq_bf + 36864;
  unsigned short* wp_bf   = wkv_bf + 73728;
  float* bias_f           = (float*)outc;               // 2,897,664 B
  float* mask_f           = (float*)(outc + 2897664);   // 30,908,416 B (end 33.8MB < 67.4MB)

  hipLaunchKernelGGL(precompute, dim3(8926), dim3(256), 0, stream,
                     mask, table, rel_idx, qw, kvw, pw,
                     wq_bf, wkv_bf, wp_bf, bias_f, mask_f, v_frag);
  hipLaunchKernelGGL(proj, dim3(768, 3), dim3(256), 0, stream,
                     x1, x2, wq_bf, wkv_bf, qb, kvb, q_g, k_g, v_frag);
  hipLaunchKernelGGL(attn, dim3(1536), dim3(512), 0, stream,
                     q_g, k_g, v_frag, bias_f, mask_f, a_o);
  hipLaunchKernelGGL(proj_out, dim3(686), dim3(256), 0, stream,
                     a_o, wp_bf, pb, (float*)d_out);
}

// Round 15
// 222.292 us; speedup vs baseline: 1.3540x; 1.3540x over previous
//
#include <hip/hip_runtime.h>

typedef __attribute__((ext_vector_type(8))) short short8;
typedef __attribute__((ext_vector_type(4))) float f32x4;
typedef __attribute__((ext_vector_type(16))) float f32x16;
typedef __attribute__((ext_vector_type(4))) unsigned short us4;
typedef __attribute__((ext_vector_type(2))) unsigned int u32x2;

#define NTOK 343
#define BMP 352      // bias/mask padded row pitch (elements)
#define LOG2E 1.4426950408889634f
#define FPLANE 11264 // shorts per (b,h) fragment plane: 11 tiles x 1024
#define WPITCH 200   // LDS W row pitch (shorts)

// ---- workspace layout (bytes) ----
#define OFF_QG   0u            // q: [bh][tok][32]            33,718,272
#define OFF_KG   33718272u     // k frag planes: 1536*11264*2 34,603,008
#define OFF_VT   68321280u     // v frag planes               34,603,008
#define OFF_AO   102924288u    // attn out                    33,718,272
#define OFF_WB   136642560u    // bf16 weights
// bf16 bias/mask tables live in d_out scratch (dead before proj_out writes)

__device__ __forceinline__ unsigned short f2bf(float f) {
  union { float f; unsigned u; } v; v.f = f;
  unsigned r = v.u + 0x7FFFu + ((v.u >> 16) & 1u);
  return (unsigned short)(r >> 16);
}

__device__ __forceinline__ float bf2f(unsigned short b) {
  union { unsigned u; float f; } v; v.u = ((unsigned)b) << 16;
  return v.f;
}

__device__ __forceinline__ short8 ld8(const unsigned short* p) {
  return *reinterpret_cast<const short8*>(p);
}

__device__ __forceinline__ float fexp2(float x) {
  float r; asm("v_exp_f32 %0, %1" : "=v"(r) : "v"(x)); return r;
}

__device__ __forceinline__ unsigned cvtpk(float a, float b) {
  unsigned r; asm("v_cvt_pk_bf16_f32 %0, %1, %2" : "=v"(r) : "v"(a), "v"(b)); return r;
}

// D' = {D.lo32lanes, S.lo32lanes}; S' = {D.hi32lanes, S.hi32lanes}
__device__ __forceinline__ void plswap(unsigned &a, unsigned &b) {
  asm("v_permlane32_swap_b32 %0, %1" : "+v"(a), "+v"(b));
}

__device__ __forceinline__ f32x16 mfma32(short8 a, short8 b, f32x16 c) {
  return __builtin_amdgcn_mfma_f32_32x32x16_bf16(a, b, c, 0, 0, 0);
}

__device__ __forceinline__ f32x4 mfma16(short8 a, short8 b, f32x4 c) {
  return __builtin_amdgcn_mfma_f32_16x16x32_bf16(a, b, c, 0, 0, 0);
}

union frag_u { unsigned u[4]; short8 s8; };

// pack 8 consecutive f32 -> bf16x8 fragment
__device__ __forceinline__ short8 cvt8f(const float* p) {
  f32x4 a = *reinterpret_cast<const f32x4*>(p);
  f32x4 b = *reinterpret_cast<const f32x4*>(p + 4);
  frag_u f;
  f.u[0] = cvtpk(a[0], a[1]); f.u[1] = cvtpk(a[2], a[3]);
  f.u[2] = cvtpk(b[0], b[1]); f.u[3] = cvtpk(b[2], b[3]);
  return f.s8;
}

// ---------------- kernel B: precompute (weights, mask, bias, pads) ----------------
__global__ __launch_bounds__(256) void precompute(
    const float* __restrict__ mask, const float* __restrict__ table,
    const int* __restrict__ rel_idx,
    const float* __restrict__ qw, const float* __restrict__ kvw, const float* __restrict__ pw,
    unsigned short* __restrict__ wq_bf, unsigned short* __restrict__ wkv_bf,
    unsigned short* __restrict__ wp_bf,
    unsigned short* __restrict__ bias_bf, unsigned short* __restrict__ mask_bf,
    unsigned short* __restrict__ v_frag)
{
  const int idx = blockIdx.x * 256 + threadIdx.x;
  if (idx < 36864) {
    const int wi = idx;
    const float* src; unsigned short* dst; int i;
    if (wi < 9216)       { src = qw;  dst = wq_bf;  i = wi; }
    else if (wi < 27648) { src = kvw; dst = wkv_bf; i = wi - 9216; }
    else                 { src = pw;  dst = wp_bf;  i = wi - 27648; }
    f32x4 v = *reinterpret_cast<const f32x4*>(src + i * 4);
    us4 o; o[0] = f2bf(v[0]); o[1] = f2bf(v[1]); o[2] = f2bf(v[2]); o[3] = f2bf(v[3]);
    *reinterpret_cast<us4*>(dst + i * 4) = o;
  } else if (idx < 1968640) {
    const int mi = idx - 36864;
    const int row = mi / 88, q = mi - row * 88;
    const int j0 = q * 4;
    unsigned short* dst = mask_bf + row * BMP + j0;
    if (q < 85) {
      const float* src = mask + row * NTOK + j0;
      us4 o; o[0] = f2bf(LOG2E * src[0]); o[1] = f2bf(LOG2E * src[1]);
      o[2] = f2bf(LOG2E * src[2]); o[3] = f2bf(LOG2E * src[3]);
      *reinterpret_cast<us4*>(dst) = o;
    } else {
      us4 o;
      #pragma unroll
      for (int i = 0; i < 4; ++i) {
        const int col = j0 + i;
        o[i] = (col < NTOK) ? f2bf(LOG2E * mask[row * NTOK + col]) : (unsigned short)0;
      }
      *reinterpret_cast<us4*>(dst) = o;
    }
  } else if (idx < 2086289) {
    const int i = idx - 1968640;
    const int ri = rel_idx[i] * 6;
    const int rrow = i / NTOK, j = i - rrow * NTOK;
    unsigned short* dst = bias_bf + rrow * BMP + j;
    #pragma unroll
    for (int h = 0; h < 6; ++h) dst[h * (NTOK * BMP)] = f2bf(LOG2E * table[ri + h]);
  } else if (idx < 2088347) {
    const int p = idx - 2086289;
    unsigned short* dst = bias_bf + p * BMP + NTOK;
    #pragma unroll
    for (int c = 0; c < 9; ++c) dst[c] = 0;
  } else if (idx < 2284955) {
    const int i = idx - 2088347;
    const int bh = i >> 7, c = i & 127;
    short8 z = (short8){0,0,0,0,0,0,0,0};
    *reinterpret_cast<short8*>(v_frag + bh * FPLANE + 10240 + c * 8) = z;
  }
}

// ---------------- kernel A: fused Q/K/V projection (f32 X, LDS-W, per-window tiles) ----------------
__global__ __launch_bounds__(256) void proj(
    const float* __restrict__ x1f, const float* __restrict__ x2f,
    const unsigned short* __restrict__ wq_bf, const unsigned short* __restrict__ wkv_bf,
    const float* __restrict__ qb, const float* __restrict__ kvb,
    unsigned short* __restrict__ q_g, unsigned short* __restrict__ k_g,
    unsigned short* __restrict__ v_frag)
{
  __shared__ __align__(16) unsigned short wLds[192 * WPITCH];

  const int tid = threadIdx.x;
  const int wv = tid >> 6, lane = tid & 63, lg = lane >> 4, lr = lane & 15;
  const int path = blockIdx.y;
  const int b = blockIdx.x & 255, seg = blockIdx.x >> 8;
  const int n0 = seg * 128 + wv * 32;

  const float* X = (path == 0) ? x1f : x2f;
  const unsigned short* Wsrc = (path == 0) ? wq_bf : (path == 1 ? wkv_bf : wkv_bf + 36864);

  #pragma unroll
  for (int i = 0; i < 18; ++i) {
    const int c = i * 256 + tid;
    const int row = c / 24, c8 = c - row * 24;
    *reinterpret_cast<short8*>(&wLds[row * WPITCH + c8 * 8]) = ld8(Wsrc + row * 192 + c8 * 8);
  }
  __syncthreads();

  const int rowbase = b * NTOK;
  const int nA = n0 + lr, nB = n0 + 16 + lr;
  const float* xr0 = X + (rowbase + (nA < NTOK ? nA : NTOK - 1)) * 192 + lg * 8;
  const float* xr1 = X + (rowbase + (nB < NTOK ? nB : NTOK - 1)) * 192 + lg * 8;

  short8 ax[2][6];
  #pragma unroll
  for (int kk = 0; kk < 6; ++kk) {
    ax[0][kk] = cvt8f(xr0 + kk * 32);
    ax[1][kk] = cvt8f(xr1 + kk * 32);
  }

  f32x4 acc[2][12];
  #pragma unroll
  for (int i = 0; i < 2; ++i)
    #pragma unroll
    for (int j = 0; j < 12; ++j) acc[i][j] = (f32x4){0.f, 0.f, 0.f, 0.f};

  if (path < 2) {
    #pragma unroll
    for (int kk = 0; kk < 6; ++kk) {
      const int k0 = kk * 32 + lg * 8;
      #pragma unroll
      for (int ct = 0; ct < 12; ++ct) {
        const short8 wf = *reinterpret_cast<const short8*>(&wLds[(ct * 16 + lr) * WPITCH + k0]);
        acc[0][ct] = mfma16(wf, ax[0][kk], acc[0][ct]);
        acc[1][ct] = mfma16(wf, ax[1][kk], acc[1][ct]);
      }
    }
    if (path == 0) {
      const float qs = 0.17677669529663687f * LOG2E;
      #pragma unroll
      for (int tt = 0; tt < 2; ++tt) {
        const int n = n0 + tt * 16 + lr;
        if (n < NTOK) {
          unsigned short* ob = q_g + (b * 6 * NTOK + n) * 32;
          #pragma unroll
          for (int ct = 0; ct < 12; ++ct) {
            const f32x4 bb = *reinterpret_cast<const f32x4*>(qb + ct * 16 + lg * 4);
            u32x2 pk;
            pk[0] = cvtpk((acc[tt][ct][0] + bb[0]) * qs, (acc[tt][ct][1] + bb[1]) * qs);
            pk[1] = cvtpk((acc[tt][ct][2] + bb[2]) * qs, (acc[tt][ct][3] + bb[3]) * qs);
            *reinterpret_cast<u32x2*>(ob + (ct >> 1) * (NTOK * 32) + (ct & 1) * 16 + lg * 4) = pk;
          }
        }
      }
    } else {
      #pragma unroll
      for (int tt = 0; tt < 2; ++tt) {
        const int n = n0 + tt * 16 + lr;
        if (n < 352) {
          unsigned short* ob = k_g + b * 6 * FPLANE + (n >> 5) * 1024
                               + ((lg >> 1) * 32 + (n & 31)) * 8 + (lg & 1) * 4;
          #pragma unroll
          for (int ct = 0; ct < 12; ++ct) {
            const f32x4 bb = *reinterpret_cast<const f32x4*>(kvb + ct * 16 + lg * 4);
            u32x2 pk;
            pk[0] = cvtpk(acc[tt][ct][0] + bb[0], acc[tt][ct][1] + bb[1]);
            pk[1] = cvtpk(acc[tt][ct][2] + bb[2], acc[tt][ct][3] + bb[3]);
            *reinterpret_cast<u32x2*>(ob + (ct >> 1) * FPLANE + (ct & 1) * 512) = pk;
          }
        }
      }
    }
  } else {
    #pragma unroll
    for (int kk = 0; kk < 6; ++kk) {
      const int k0 = kk * 32 + lg * 8;
      #pragma unroll
      for (int ct = 0; ct < 12; ++ct) {
        const short8 wf = *reinterpret_cast<const short8*>(&wLds[(ct * 16 + lr) * WPITCH + k0]);
        acc[0][ct] = mfma16(ax[0][kk], wf, acc[0][ct]);
        acc[1][ct] = mfma16(ax[1][kk], wf, acc[1][ct]);
      }
    }
    float bs[12];
    #pragma unroll
    for (int ct = 0; ct < 12; ++ct) bs[ct] = kvb[192 + ct * 16 + lr];
    #pragma unroll
    for (int tt = 0; tt < 2; ++tt) {
      const int nb = n0 + tt * 16 + lg * 4;
      if (nb < 352) {
        unsigned short* vb = v_frag + b * 6 * FPLANE + (nb >> 5) * 1024
                             + ((nb >> 4) & 1) * 512 + ((nb >> 3) & 1) * 256 + (nb & 7);
        #pragma unroll
        for (int ct = 0; ct < 12; ++ct) {
          const int d = (ct & 1) * 16 + lr;
          u32x2 pk;
          pk[0] = cvtpk(acc[tt][ct][0] + bs[ct], acc[tt][ct][1] + bs[ct]);
          pk[1] = cvtpk(acc[tt][ct][2] + bs[ct], acc[tt][ct][3] + bs[ct]);
          *reinterpret_cast<u32x2*>(vb + (ct >> 1) * FPLANE + d * 8) = pk;
        }
      }
    }
  }
}

// ---------------- kernel C: attention v15 (r13 core; 2 blocks per (b,h): qt groups {0..5}/{6..10}) ----------------
__global__ __launch_bounds__(256, 3) void attn(
    const unsigned short* __restrict__ q_g, const unsigned short* __restrict__ k_g,
    const unsigned short* __restrict__ v_frag, const unsigned short* __restrict__ bias_bf,
    const unsigned short* __restrict__ mask_bf, unsigned short* __restrict__ attn_out)
{
  __shared__ __align__(16) unsigned short kvlds[2][FPLANE];

  const int tid = threadIdx.x;
  const int wv = tid >> 6, lane = tid & 63;
  const int l31 = lane & 31, hi = lane >> 5;
  // XCD-bijective decode: 4 b's sharing a (w,h) bias/mask panel land on one XCD
  const int s0 = blockIdx.x;
  const int grp = blockIdx.y;           // qt group: 0 -> tiles 0..5, 1 -> tiles 6..10
  const int xcd = s0 & 7, ii = s0 >> 3;
  const int g = xcd * 48 + (ii >> 2), mem = ii & 3;
  const int h = g >> 6, w = g & 63;
  const int b = mem * 64 + w;
  const int bid = b * 6 + h;

  const unsigned short* qp = q_g + bid * (NTOK * 32);
  const unsigned short* kpf = k_g + bid * FPLANE;
  const unsigned short* vpf = v_frag + bid * FPLANE;
  const unsigned short* bias_h = bias_bf + h * (NTOK * BMP);
  const unsigned short* mask_w = mask_bf + w * (NTOK * BMP);

  // stage K and V planes (linear copy, coalesced, conflict-free)
  #pragma unroll
  for (int j = 0; j < 6; ++j) {
    const int c = j * 256 + tid;
    if (c < 1408) {
      *reinterpret_cast<short8*>(&kvlds[0][c * 8]) = ld8(kpf + c * 8);
      *reinterpret_cast<short8*>(&kvlds[1][c * 8]) = ld8(vpf + c * 8);
    }
  }
  __syncthreads();

  const int qt_end = grp ? 11 : 6;
  for (int qt = grp * 6 + wv; qt < qt_end; qt += 4) {
    const int qq = qt * 32 + l31;
    const int qrc = qq < NTOK ? qq : NTOK - 1;
    const short8 qf0 = ld8(qp + qrc * 32 + hi * 8);
    const short8 qf1 = ld8(qp + qrc * 32 + 16 + hi * 8);
    const unsigned short* bmb = bias_h + qrc * BMP + hi * 4;
    const unsigned short* bmm = mask_w + qrc * BMP + hi * 4;

    f32x16 O;
    #pragma unroll
    for (int r = 0; r < 16; ++r) O[r] = 0.f;
    f32x4 sacc = (f32x4){0.f, 0.f, 0.f, 0.f};

    // prefetch bias/mask for kt=0
    us4 nb[4], nm[4];
    #pragma unroll
    for (int gg = 0; gg < 4; ++gg) {
      nb[gg] = *reinterpret_cast<const us4*>(bmb + gg * 8);
      nm[gg] = *reinterpret_cast<const us4*>(bmm + gg * 8);
    }

    #pragma unroll
    for (int kt = 0; kt < 11; ++kt) {
      us4 cb[4], cm[4];
      #pragma unroll
      for (int gg = 0; gg < 4; ++gg) { cb[gg] = nb[gg]; cm[gg] = nm[gg]; }
      if (kt < 10) {
        const int kn = (kt + 1) * 32;
        #pragma unroll
        for (int gg = 0; gg < 4; ++gg) {
          nb[gg] = *reinterpret_cast<const us4*>(bmb + kn + gg * 8);
          nm[gg] = *reinterpret_cast<const us4*>(bmm + kn + gg * 8);
        }
      }

      // S^T tile from LDS fragments
      const short8 kf0 = ld8(&kvlds[0][kt * 1024 + lane * 8]);
      const short8 kf1 = ld8(&kvlds[0][kt * 1024 + 512 + lane * 8]);
      f32x16 sv;
      #pragma unroll
      for (int r = 0; r < 16; ++r) sv[r] = 0.f;
      __builtin_amdgcn_s_setprio(1);
      sv = mfma32(kf0, qf0, sv);
      sv = mfma32(kf1, qf1, sv);
      __builtin_amdgcn_s_setprio(0);

      // p = exp2(S + bias + mask) — no max subtraction (inputs bounded, f32-safe)
      float p[16];
      #pragma unroll
      for (int gg = 0; gg < 4; ++gg) {
        #pragma unroll
        for (int j = 0; j < 4; ++j) {
          float v = sv[gg * 4 + j] + (bf2f(cb[gg][j]) + bf2f(cm[gg][j]));
          if (kt == 10 && (gg * 8 + hi * 4 + j) >= 23) v = -3.0e38f;
          p[gg * 4 + j] = fexp2(v);
        }
      }
      #pragma unroll
      for (int j = 0; j < 4; ++j)
        sacc[j] += (p[j] + p[4 + j]) + (p[8 + j] + p[12 + j]);

      unsigned c01 = cvtpk(p[0], p[1]),   c23 = cvtpk(p[2], p[3]);
      unsigned c45 = cvtpk(p[4], p[5]),   c67 = cvtpk(p[6], p[7]);
      unsigned d01 = cvtpk(p[8], p[9]),   d23 = cvtpk(p[10], p[11]);
      unsigned d45 = cvtpk(p[12], p[13]), d67 = cvtpk(p[14], p[15]);
      plswap(c01, c45); plswap(c23, c67);
      plswap(d01, d45); plswap(d23, d67);
      frag_u P0, P1;
      P0.u[0] = c01; P0.u[1] = c23; P0.u[2] = c45; P0.u[3] = c67;
      P1.u[0] = d01; P1.u[1] = d23; P1.u[2] = d45; P1.u[3] = d67;

      const short8 vf0 = ld8(&kvlds[1][kt * 1024 + lane * 8]);
      const short8 vf1 = ld8(&kvlds[1][kt * 1024 + 512 + lane * 8]);
      __builtin_amdgcn_s_setprio(1);
      O = mfma32(vf0, P0.s8, O);
      O = mfma32(vf1, P1.s8, O);
      __builtin_amdgcn_s_setprio(0);
    }

    float sum = (sacc[0] + sacc[1]) + (sacc[2] + sacc[3]);
    sum += __shfl_xor(sum, 32);
    const float inv = 1.0f / sum;
    if (qq < NTOK) {
      unsigned short* op = attn_out + (b * NTOK + qq) * 192 + h * 32;
      #pragma unroll
      for (int gg = 0; gg < 4; ++gg) {
        us4 ov;
        #pragma unroll
        for (int j = 0; j < 4; ++j) ov[j] = f2bf(O[gg * 4 + j] * inv);
        *reinterpret_cast<us4*>(op + gg * 8 + hi * 4) = ov;
      }
    }
  }
}

// ---------------- kernel D: output projection (LDS-W, swapped, f32x4 stores) ----------------
__global__ __launch_bounds__(256) void proj_out(
    const unsigned short* __restrict__ a_in, const unsigned short* __restrict__ wp_bf,
    const float* __restrict__ pb, float* __restrict__ out)
{
  __shared__ __align__(16) unsigned short wLds[192 * WPITCH];

  const int tid = threadIdx.x;
  const int wv = tid >> 6, lane = tid & 63, lg = lane >> 4, lr = lane & 15;
  const int t0 = blockIdx.x * 128 + wv * 32;

  #pragma unroll
  for (int i = 0; i < 18; ++i) {
    const int c = i * 256 + tid;
    const int row = c / 24, c8 = c - row * 24;
    *reinterpret_cast<short8*>(&wLds[row * WPITCH + c8 * 8]) = ld8(wp_bf + row * 192 + c8 * 8);
  }
  __syncthreads();

  const unsigned short* xr0 = a_in + (t0 + lr) * 192 + lg * 8;
  const unsigned short* xr1 = xr0 + 16 * 192;

  short8 ax[2][6];
  #pragma unroll
  for (int kk = 0; kk < 6; ++kk) {
    ax[0][kk] = ld8(xr0 + kk * 32);
    ax[1][kk] = ld8(xr1 + kk * 32);
  }

  f32x4 acc[2][12];
  #pragma unroll
  for (int i = 0; i < 2; ++i)
    #pragma unroll
    for (int j = 0; j < 12; ++j) acc[i][j] = (f32x4){0.f, 0.f, 0.f, 0.f};

  #pragma unroll
  for (int kk = 0; kk < 6; ++kk) {
    const int k0 = kk * 32 + lg * 8;
    #pragma unroll
    for (int ct = 0; ct < 12; ++ct) {
      const short8 wf = *reinterpret_cast<const short8*>(&wLds[(ct * 16 + lr) * WPITCH + k0]);
      acc[0][ct] = mfma16(wf, ax[0][kk], acc[0][ct]);
      acc[1][ct] = mfma16(wf, ax[1][kk], acc[1][ct]);
    }
  }

  #pragma unroll
  for (int tt = 0; tt < 2; ++tt) {
    const int t = t0 + tt * 16 + lr;
    float* op = out + t * 192 + lg * 4;
    #pragma unroll
    for (int ct = 0; ct < 12; ++ct) {
      const f32x4 bb = *reinterpret_cast<const f32x4*>(pb + ct * 16 + lg * 4);
      f32x4 ov;
      #pragma unroll
      for (int r = 0; r < 4; ++r) ov[r] = acc[tt][ct][r] + bb[r];
      *reinterpret_cast<f32x4*>(op + ct * 16) = ov;
    }
  }
}

extern "C" void kernel_launch(void* const* d_in, const int* in_sizes, int n_in,
                              void* d_out, int out_size, void* d_ws, size_t ws_size,
                              hipStream_t stream) {
  const float* x1    = (const float*)d_in[0];
  const float* x2    = (const float*)d_in[1];
  const float* mask  = (const float*)d_in[2];
  const float* table = (const float*)d_in[3];
  const float* qw    = (const float*)d_in[4];
  const float* qb    = (const float*)d_in[5];
  const float* kvw   = (const float*)d_in[6];
  const float* kvb   = (const float*)d_in[7];
  const float* pw    = (const float*)d_in[8];
  const float* pb    = (const float*)d_in[9];
  const int* rel_idx = (const int*)d_in[10];

  char* ws = (char*)d_ws;
  char* outc = (char*)d_out;
  unsigned short* q_g     = (unsigned short*)(ws + OFF_QG);
  unsigned short* k_g     = (unsigned short*)(ws + OFF_KG);
  unsigned short* v_frag  = (unsigned short*)(ws + OFF_VT);
  unsigned short* a_o     = (unsigned short*)(ws + OFF_AO);
  unsigned short* wq_bf   = (unsigned short*)(ws + OFF_WB);
  unsigned short* wkv_bf  = wq_bf + 36864;
  unsigned short* wp_bf   = wkv_bf + 73728;
  unsigned short* bias_bf = (unsigned short*)(outc + 33718272);
  unsigned short* mask_bf = (unsigned short*)(outc + 35167104);

  hipLaunchKernelGGL(precompute, dim3(8926), dim3(256), 0, stream,
                     mask, table, rel_idx, qw, kvw, pw,
                     wq_bf, wkv_bf, wp_bf, bias_bf, mask_bf, v_frag);
  hipLaunchKernelGGL(proj, dim3(768, 3), dim3(256), 0, stream,
                     x1, x2, wq_bf, wkv_bf, qb, kvb, q_g, k_g, v_frag);
  hipLaunchKernelGGL(attn, dim3(1536, 2), dim3(256), 0, stream,
                     q_g, k_g, v_frag, bias_bf, mask_bf, a_o);
  hipLaunchKernelGGL(proj_out, dim3(686), dim3(256), 0, stream,
                     a_o, wp_bf, pb, (float*)d_out);
}

// Round 17
// 218.120 us; speedup vs baseline: 1.3799x; 1.0191x over previous
//
#include <hip/hip_runtime.h>

typedef __attribute__((ext_vector_type(8))) short short8;
typedef __attribute__((ext_vector_type(4))) float f32x4;
typedef __attribute__((ext_vector_type(16))) float f32x16;
typedef __attribute__((ext_vector_type(4))) unsigned short us4;
typedef __attribute__((ext_vector_type(2))) unsigned int u32x2;

#define NTOK 343
#define BMP 352      // bias/mask padded row pitch (elements)
#define LOG2E 1.4426950408889634f
#define FPLANE 11264 // shorts per (b,h) fragment plane: 11 tiles x 1024
#define WPITCH 200   // LDS W row pitch (shorts)

// ---- workspace layout (bytes) ----
#define OFF_QG   0u            // q: [bh][tok][32]            33,718,272
#define OFF_KG   33718272u     // k frag planes: 1536*11264*2 34,603,008
#define OFF_VT   68321280u     // v frag planes               34,603,008
#define OFF_AO   102924288u    // attn out                    33,718,272
#define OFF_WB   136642560u    // bf16 weights
// bf16 bias/mask tables live in d_out scratch (dead before proj_out writes)

__device__ __forceinline__ unsigned short f2bf(float f) {
  union { float f; unsigned u; } v; v.f = f;
  unsigned r = v.u + 0x7FFFu + ((v.u >> 16) & 1u);
  return (unsigned short)(r >> 16);
}

__device__ __forceinline__ float bf2f(unsigned short b) {
  union { unsigned u; float f; } v; v.u = ((unsigned)b) << 16;
  return v.f;
}

__device__ __forceinline__ short8 ld8(const unsigned short* p) {
  return *reinterpret_cast<const short8*>(p);
}

__device__ __forceinline__ float fexp2(float x) {
  float r; asm("v_exp_f32 %0, %1" : "=v"(r) : "v"(x)); return r;
}

__device__ __forceinline__ unsigned cvtpk(float a, float b) {
  unsigned r; asm("v_cvt_pk_bf16_f32 %0, %1, %2" : "=v"(r) : "v"(a), "v"(b)); return r;
}

// D' = {D.lo32lanes, S.lo32lanes}; S' = {D.hi32lanes, S.hi32lanes}
__device__ __forceinline__ void plswap(unsigned &a, unsigned &b) {
  asm("v_permlane32_swap_b32 %0, %1" : "+v"(a), "+v"(b));
}

__device__ __forceinline__ f32x16 mfma32(short8 a, short8 b, f32x16 c) {
  return __builtin_amdgcn_mfma_f32_32x32x16_bf16(a, b, c, 0, 0, 0);
}

__device__ __forceinline__ f32x4 mfma16(short8 a, short8 b, f32x4 c) {
  return __builtin_amdgcn_mfma_f32_16x16x32_bf16(a, b, c, 0, 0, 0);
}

union frag_u { unsigned u[4]; short8 s8; };

// pack 8 consecutive f32 -> bf16x8 fragment
__device__ __forceinline__ short8 cvt8f(const float* p) {
  f32x4 a = *reinterpret_cast<const f32x4*>(p);
  f32x4 b = *reinterpret_cast<const f32x4*>(p + 4);
  frag_u f;
  f.u[0] = cvtpk(a[0], a[1]); f.u[1] = cvtpk(a[2], a[3]);
  f.u[2] = cvtpk(b[0], b[1]); f.u[3] = cvtpk(b[2], b[3]);
  return f.s8;
}

// ---------------- kernel B: precompute (weights, mask, bias, pads) ----------------
__global__ __launch_bounds__(256) void precompute(
    const float* __restrict__ mask, const float* __restrict__ table,
    const int* __restrict__ rel_idx,
    const float* __restrict__ qw, const float* __restrict__ kvw, const float* __restrict__ pw,
    unsigned short* __restrict__ wq_bf, unsigned short* __restrict__ wkv_bf,
    unsigned short* __restrict__ wp_bf,
    unsigned short* __restrict__ bias_bf, unsigned short* __restrict__ mask_bf,
    unsigned short* __restrict__ v_frag)
{
  const int idx = blockIdx.x * 256 + threadIdx.x;
  if (idx < 36864) {
    const int wi = idx;
    const float* src; unsigned short* dst; int i;
    if (wi < 9216)       { src = qw;  dst = wq_bf;  i = wi; }
    else if (wi < 27648) { src = kvw; dst = wkv_bf; i = wi - 9216; }
    else                 { src = pw;  dst = wp_bf;  i = wi - 27648; }
    f32x4 v = *reinterpret_cast<const f32x4*>(src + i * 4);
    us4 o; o[0] = f2bf(v[0]); o[1] = f2bf(v[1]); o[2] = f2bf(v[2]); o[3] = f2bf(v[3]);
    *reinterpret_cast<us4*>(dst + i * 4) = o;
  } else if (idx < 1968640) {
    const int mi = idx - 36864;
    const int row = mi / 88, q = mi - row * 88;
    const int j0 = q * 4;
    unsigned short* dst = mask_bf + row * BMP + j0;
    if (q < 85) {
      const float* src = mask + row * NTOK + j0;
      us4 o; o[0] = f2bf(LOG2E * src[0]); o[1] = f2bf(LOG2E * src[1]);
      o[2] = f2bf(LOG2E * src[2]); o[3] = f2bf(LOG2E * src[3]);
      *reinterpret_cast<us4*>(dst) = o;
    } else {
      us4 o;
      #pragma unroll
      for (int i = 0; i < 4; ++i) {
        const int col = j0 + i;
        o[i] = (col < NTOK) ? f2bf(LOG2E * mask[row * NTOK + col]) : (unsigned short)0;
      }
      *reinterpret_cast<us4*>(dst) = o;
    }
  } else if (idx < 2086289) {
    const int i = idx - 1968640;
    const int ri = rel_idx[i] * 6;
    const int rrow = i / NTOK, j = i - rrow * NTOK;
    unsigned short* dst = bias_bf + rrow * BMP + j;
    #pragma unroll
    for (int h = 0; h < 6; ++h) dst[h * (NTOK * BMP)] = f2bf(LOG2E * table[ri + h]);
  } else if (idx < 2088347) {
    const int p = idx - 2086289;
    unsigned short* dst = bias_bf + p * BMP + NTOK;
    #pragma unroll
    for (int c = 0; c < 9; ++c) dst[c] = 0;
  } else if (idx < 2284955) {
    const int i = idx - 2088347;
    const int bh = i >> 7, c = i & 127;
    short8 z = (short8){0,0,0,0,0,0,0,0};
    *reinterpret_cast<short8*>(v_frag + bh * FPLANE + 10240 + c * 8) = z;
  }
}

// ---------------- kernel A: fused Q/K/V projection (f32 X, LDS-W, per-window tiles) ----------------
__global__ __launch_bounds__(256) void proj(
    const float* __restrict__ x1f, const float* __restrict__ x2f,
    const unsigned short* __restrict__ wq_bf, const unsigned short* __restrict__ wkv_bf,
    const float* __restrict__ qb, const float* __restrict__ kvb,
    unsigned short* __restrict__ q_g, unsigned short* __restrict__ k_g,
    unsigned short* __restrict__ v_frag)
{
  __shared__ __align__(16) unsigned short wLds[192 * WPITCH];

  const int tid = threadIdx.x;
  const int wv = tid >> 6, lane = tid & 63, lg = lane >> 4, lr = lane & 15;
  const int path = blockIdx.y;
  const int b = blockIdx.x & 255, seg = blockIdx.x >> 8;
  const int n0 = seg * 128 + wv * 32;

  const float* X = (path == 0) ? x1f : x2f;
  const unsigned short* Wsrc = (path == 0) ? wq_bf : (path == 1 ? wkv_bf : wkv_bf + 36864);

  #pragma unroll
  for (int i = 0; i < 18; ++i) {
    const int c = i * 256 + tid;
    const int row = c / 24, c8 = c - row * 24;
    *reinterpret_cast<short8*>(&wLds[row * WPITCH + c8 * 8]) = ld8(Wsrc + row * 192 + c8 * 8);
  }
  __syncthreads();

  const int rowbase = b * NTOK;
  const int nA = n0 + lr, nB = n0 + 16 + lr;
  const float* xr0 = X + (rowbase + (nA < NTOK ? nA : NTOK - 1)) * 192 + lg * 8;
  const float* xr1 = X + (rowbase + (nB < NTOK ? nB : NTOK - 1)) * 192 + lg * 8;

  short8 ax[2][6];
  #pragma unroll
  for (int kk = 0; kk < 6; ++kk) {
    ax[0][kk] = cvt8f(xr0 + kk * 32);
    ax[1][kk] = cvt8f(xr1 + kk * 32);
  }

  f32x4 acc[2][12];
  #pragma unroll
  for (int i = 0; i < 2; ++i)
    #pragma unroll
    for (int j = 0; j < 12; ++j) acc[i][j] = (f32x4){0.f, 0.f, 0.f, 0.f};

  if (path < 2) {
    #pragma unroll
    for (int kk = 0; kk < 6; ++kk) {
      const int k0 = kk * 32 + lg * 8;
      #pragma unroll
      for (int ct = 0; ct < 12; ++ct) {
        const short8 wf = *reinterpret_cast<const short8*>(&wLds[(ct * 16 + lr) * WPITCH + k0]);
        acc[0][ct] = mfma16(wf, ax[0][kk], acc[0][ct]);
        acc[1][ct] = mfma16(wf, ax[1][kk], acc[1][ct]);
      }
    }
    if (path == 0) {
      const float qs = 0.17677669529663687f * LOG2E;
      #pragma unroll
      for (int tt = 0; tt < 2; ++tt) {
        const int n = n0 + tt * 16 + lr;
        if (n < NTOK) {
          unsigned short* ob = q_g + (b * 6 * NTOK + n) * 32;
          #pragma unroll
          for (int ct = 0; ct < 12; ++ct) {
            const f32x4 bb = *reinterpret_cast<const f32x4*>(qb + ct * 16 + lg * 4);
            u32x2 pk;
            pk[0] = cvtpk((acc[tt][ct][0] + bb[0]) * qs, (acc[tt][ct][1] + bb[1]) * qs);
            pk[1] = cvtpk((acc[tt][ct][2] + bb[2]) * qs, (acc[tt][ct][3] + bb[3]) * qs);
            *reinterpret_cast<u32x2*>(ob + (ct >> 1) * (NTOK * 32) + (ct & 1) * 16 + lg * 4) = pk;
          }
        }
      }
    } else {
      #pragma unroll
      for (int tt = 0; tt < 2; ++tt) {
        const int n = n0 + tt * 16 + lr;
        if (n < 352) {
          unsigned short* ob = k_g + b * 6 * FPLANE + (n >> 5) * 1024
                               + ((lg >> 1) * 32 + (n & 31)) * 8 + (lg & 1) * 4;
          #pragma unroll
          for (int ct = 0; ct < 12; ++ct) {
            const f32x4 bb = *reinterpret_cast<const f32x4*>(kvb + ct * 16 + lg * 4);
            u32x2 pk;
            pk[0] = cvtpk(acc[tt][ct][0] + bb[0], acc[tt][ct][1] + bb[1]);
            pk[1] = cvtpk(acc[tt][ct][2] + bb[2], acc[tt][ct][3] + bb[3]);
            *reinterpret_cast<u32x2*>(ob + (ct >> 1) * FPLANE + (ct & 1) * 512) = pk;
          }
        }
      }
    }
  } else {
    #pragma unroll
    for (int kk = 0; kk < 6; ++kk) {
      const int k0 = kk * 32 + lg * 8;
      #pragma unroll
      for (int ct = 0; ct < 12; ++ct) {
        const short8 wf = *reinterpret_cast<const short8*>(&wLds[(ct * 16 + lr) * WPITCH + k0]);
        acc[0][ct] = mfma16(ax[0][kk], wf, acc[0][ct]);
        acc[1][ct] = mfma16(ax[1][kk], wf, acc[1][ct]);
      }
    }
    float bs[12];
    #pragma unroll
    for (int ct = 0; ct < 12; ++ct) bs[ct] = kvb[192 + ct * 16 + lr];
    #pragma unroll
    for (int tt = 0; tt < 2; ++tt) {
      const int nb = n0 + tt * 16 + lg * 4;
      if (nb < 352) {
        unsigned short* vb = v_frag + b * 6 * FPLANE + (nb >> 5) * 1024
                             + ((nb >> 4) & 1) * 512 + ((nb >> 3) & 1) * 256 + (nb & 7);
        #pragma unroll
        for (int ct = 0; ct < 12; ++ct) {
          const int d = (ct & 1) * 16 + lr;
          u32x2 pk;
          pk[0] = cvtpk(acc[tt][ct][0] + bs[ct], acc[tt][ct][1] + bs[ct]);
          pk[1] = cvtpk(acc[tt][ct][2] + bs[ct], acc[tt][ct][3] + bs[ct]);
          *reinterpret_cast<u32x2*>(vb + (ct >> 1) * FPLANE + d * 8) = pk;
        }
      }
    }
  }
}

// ---------------- kernel C: attention (r13: K+V in LDS, no-max softmax, permlane, setprio fences) ----------------
__global__ __launch_bounds__(256, 3) void attn(
    const unsigned short* __restrict__ q_g, const unsigned short* __restrict__ k_g,
    const unsigned short* __restrict__ v_frag, const unsigned short* __restrict__ bias_bf,
    const unsigned short* __restrict__ mask_bf, unsigned short* __restrict__ attn_out)
{
  __shared__ __align__(16) unsigned short kvlds[2][FPLANE];

  const int tid = threadIdx.x;
  const int wv = tid >> 6, lane = tid & 63;
  const int l31 = lane & 31, hi = lane >> 5;
  // XCD-bijective decode: 4 b's sharing a (w,h) bias/mask panel land on one XCD
  const int s0 = blockIdx.x;
  const int xcd = s0 & 7, ii = s0 >> 3;
  const int g = xcd * 48 + (ii >> 2), mem = ii & 3;
  const int h = g >> 6, w = g & 63;
  const int b = mem * 64 + w;
  const int bid = b * 6 + h;

  const unsigned short* qp = q_g + bid * (NTOK * 32);
  const unsigned short* kpf = k_g + bid * FPLANE;
  const unsigned short* vpf = v_frag + bid * FPLANE;
  const unsigned short* bias_h = bias_bf + h * (NTOK * BMP);
  const unsigned short* mask_w = mask_bf + w * (NTOK * BMP);

  // stage K and V planes (linear copy, coalesced, conflict-free)
  #pragma unroll
  for (int j = 0; j < 6; ++j) {
    const int c = j * 256 + tid;
    if (c < 1408) {
      *reinterpret_cast<short8*>(&kvlds[0][c * 8]) = ld8(kpf + c * 8);
      *reinterpret_cast<short8*>(&kvlds[1][c * 8]) = ld8(vpf + c * 8);
    }
  }
  __syncthreads();

  for (int qt = wv; qt < 11; qt += 4) {
    const int qq = qt * 32 + l31;
    const int qrc = qq < NTOK ? qq : NTOK - 1;
    const short8 qf0 = ld8(qp + qrc * 32 + hi * 8);
    const short8 qf1 = ld8(qp + qrc * 32 + 16 + hi * 8);
    const unsigned short* bmb = bias_h + qrc * BMP + hi * 4;
    const unsigned short* bmm = mask_w + qrc * BMP + hi * 4;

    f32x16 O;
    #pragma unroll
    for (int r = 0; r < 16; ++r) O[r] = 0.f;
    f32x4 sacc = (f32x4){0.f, 0.f, 0.f, 0.f};

    // prefetch bias/mask for kt=0
    us4 nb[4], nm[4];
    #pragma unroll
    for (int gg = 0; gg < 4; ++gg) {
      nb[gg] = *reinterpret_cast<const us4*>(bmb + gg * 8);
      nm[gg] = *reinterpret_cast<const us4*>(bmm + gg * 8);
    }

    #pragma unroll
    for (int kt = 0; kt < 11; ++kt) {
      us4 cb[4], cm[4];
      #pragma unroll
      for (int gg = 0; gg < 4; ++gg) { cb[gg] = nb[gg]; cm[gg] = nm[gg]; }
      if (kt < 10) {
        const int kn = (kt + 1) * 32;
        #pragma unroll
        for (int gg = 0; gg < 4; ++gg) {
          nb[gg] = *reinterpret_cast<const us4*>(bmb + kn + gg * 8);
          nm[gg] = *reinterpret_cast<const us4*>(bmm + kn + gg * 8);
        }
      }

      // S^T tile from LDS fragments
      const short8 kf0 = ld8(&kvlds[0][kt * 1024 + lane * 8]);
      const short8 kf1 = ld8(&kvlds[0][kt * 1024 + 512 + lane * 8]);
      f32x16 sv;
      #pragma unroll
      for (int r = 0; r < 16; ++r) sv[r] = 0.f;
      __builtin_amdgcn_s_setprio(1);
      sv = mfma32(kf0, qf0, sv);
      sv = mfma32(kf1, qf1, sv);
      __builtin_amdgcn_s_setprio(0);

      // p = exp2(S + bias + mask) — no max subtraction (inputs bounded, f32-safe)
      float p[16];
      #pragma unroll
      for (int gg = 0; gg < 4; ++gg) {
        #pragma unroll
        for (int j = 0; j < 4; ++j) {
          float v = sv[gg * 4 + j] + (bf2f(cb[gg][j]) + bf2f(cm[gg][j]));
          if (kt == 10 && (gg * 8 + hi * 4 + j) >= 23) v = -3.0e38f;
          p[gg * 4 + j] = fexp2(v);
        }
      }
      #pragma unroll
      for (int j = 0; j < 4; ++j)
        sacc[j] += (p[j] + p[4 + j]) + (p[8 + j] + p[12 + j]);

      unsigned c01 = cvtpk(p[0], p[1]),   c23 = cvtpk(p[2], p[3]);
      unsigned c45 = cvtpk(p[4], p[5]),   c67 = cvtpk(p[6], p[7]);
      unsigned d01 = cvtpk(p[8], p[9]),   d23 = cvtpk(p[10], p[11]);
      unsigned d45 = cvtpk(p[12], p[13]), d67 = cvtpk(p[14], p[15]);
      plswap(c01, c45); plswap(c23, c67);
      plswap(d01, d45); plswap(d23, d67);
      frag_u P0, P1;
      P0.u[0] = c01; P0.u[1] = c23; P0.u[2] = c45; P0.u[3] = c67;
      P1.u[0] = d01; P1.u[1] = d23; P1.u[2] = d45; P1.u[3] = d67;

      const short8 vf0 = ld8(&kvlds[1][kt * 1024 + lane * 8]);
      const short8 vf1 = ld8(&kvlds[1][kt * 1024 + 512 + lane * 8]);
      __builtin_amdgcn_s_setprio(1);
      O = mfma32(vf0, P0.s8, O);
      O = mfma32(vf1, P1.s8, O);
      __builtin_amdgcn_s_setprio(0);
    }

    float sum = (sacc[0] + sacc[1]) + (sacc[2] + sacc[3]);
    sum += __shfl_xor(sum, 32);
    const float inv = 1.0f / sum;
    if (qq < NTOK) {
      unsigned short* op = attn_out + (b * NTOK + qq) * 192 + h * 32;
      #pragma unroll
      for (int gg = 0; gg < 4; ++gg) {
        us4 ov;
        #pragma unroll
        for (int j = 0; j < 4; ++j) ov[j] = f2bf(O[gg * 4 + j] * inv);
        *reinterpret_cast<us4*>(op + gg * 8 + hi * 4) = ov;
      }
    }
  }
}

// ---------------- kernel D: output projection (LDS-W, swapped, f32x4 stores) ----------------
__global__ __launch_bounds__(256) void proj_out(
    const unsigned short* __restrict__ a_in, const unsigned short* __restrict__ wp_bf,
    const float* __restrict__ pb, float* __restrict__ out)
{
  __shared__ __align__(16) unsigned short wLds[192 * WPITCH];

  const int tid = threadIdx.x;
  const int wv = tid >> 6, lane = tid & 63, lg = lane >> 4, lr = lane & 15;
  const int t0 = blockIdx.x * 128 + wv * 32;

  #pragma unroll
  for (int i = 0; i < 18; ++i) {
    const int c = i * 256 + tid;
    const int row = c / 24, c8 = c - row * 24;
    *reinterpret_cast<short8*>(&wLds[row * WPITCH + c8 * 8]) = ld8(wp_bf + row * 192 + c8 * 8);
  }
  __syncthreads();

  const unsigned short* xr0 = a_in + (t0 + lr) * 192 + lg * 8;
  const unsigned short* xr1 = xr0 + 16 * 192;

  short8 ax[2][6];
  #pragma unroll
  for (int kk = 0; kk < 6; ++kk) {
    ax[0][kk] = ld8(xr0 + kk * 32);
    ax[1][kk] = ld8(xr1 + kk * 32);
  }

  f32x4 acc[2][12];
  #pragma unroll
  for (int i = 0; i < 2; ++i)
    #pragma unroll
    for (int j = 0; j < 12; ++j) acc[i][j] = (f32x4){0.f, 0.f, 0.f, 0.f};

  #pragma unroll
  for (int kk = 0; kk < 6; ++kk) {
    const int k0 = kk * 32 + lg * 8;
    #pragma unroll
    for (int ct = 0; ct < 12; ++ct) {
      const short8 wf = *reinterpret_cast<const short8*>(&wLds[(ct * 16 + lr) * WPITCH + k0]);
      acc[0][ct] = mfma16(wf, ax[0][kk], acc[0][ct]);
      acc[1][ct] = mfma16(wf, ax[1][kk], acc[1][ct]);
    }
  }

  #pragma unroll
  for (int tt = 0; tt < 2; ++tt) {
    const int t = t0 + tt * 16 + lr;
    float* op = out + t * 192 + lg * 4;
    #pragma unroll
    for (int ct = 0; ct < 12; ++ct) {
      const f32x4 bb = *reinterpret_cast<const f32x4*>(pb + ct * 16 + lg * 4);
      f32x4 ov;
      #pragma unroll
      for (int r = 0; r < 4; ++r) ov[r] = acc[tt][ct][r] + bb[r];
      *reinterpret_cast<f32x4*>(op + ct * 16) = ov;
    }
  }
}

extern "C" void kernel_launch(void* const* d_in, const int* in_sizes, int n_in,
                              void* d_out, int out_size, void* d_ws, size_t ws_size,
                              hipStream_t stream) {
  const float* x1    = (const float*)d_in[0];
  const float* x2    = (const float*)d_in[1];
  const float* mask  = (const float*)d_in[2];
  const float* table = (const float*)d_in[3];
  const float* qw    = (const float*)d_in[4];
  const float* qb    = (const float*)d_in[5];
  const float* kvw   = (const float*)d_in[6];
  const float* kvb   = (const float*)d_in[7];
  const float* pw    = (const float*)d_in[8];
  const float* pb    = (const float*)d_in[9];
  const int* rel_idx = (const int*)d_in[10];

  char* ws = (char*)d_ws;
  char* outc = (char*)d_out;
  unsigned short* q_g     = (unsigned short*)(ws + OFF_QG);
  unsigned short* k_g     = (unsigned short*)(ws + OFF_KG);
  unsigned short* v_frag  = (unsigned short*)(ws + OFF_VT);
  unsigned short* a_o     = (unsigned short*)(ws + OFF_AO);
  unsigned short* wq_bf   = (unsigned short*)(ws + OFF_WB);
  unsigned short* wkv_bf  = wq_bf + 36864;
  unsigned short* wp_bf   = wkv_bf + 73728;
  unsigned short* bias_bf = (unsigned short*)(outc + 33718272);
  unsigned short* mask_bf = (unsigned short*)(outc + 35167104);

  hipLaunchKernelGGL(precompute, dim3(8926), dim3(256), 0, stream,
                     mask, table, rel_idx, qw, kvw, pw,
                     wq_bf, wkv_bf, wp_bf, bias_bf, mask_bf, v_frag);
  hipLaunchKernelGGL(proj, dim3(768, 3), dim3(256), 0, stream,
                     x1, x2, wq_bf, wkv_bf, qb, kvb, q_g, k_g, v_frag);
  hipLaunchKernelGGL(attn, dim3(1536), dim3(256), 0, stream,
                     q_g, k_g, v_frag, bias_bf, mask_bf, a_o);
  hipLaunchKernelGGL(proj_out, dim3(686), dim3(256), 0, stream,
                     a_o, wp_bf, pb, (float*)d_out);
}